// Round 7
// baseline (216.743 us; speedup 1.0000x reference)
//
#include <hip/hip_runtime.h>

// B=4, C=64, H=48, HEADS=2, BSWIN=4, BIG={3,6,12,24}, SMALL={1,2,4,8}, NH=3, L=27, CPH=8
// channel c = scale*16 + head*8 + cph ; windows per (b,head): 4096+512+64+8 = 4680

static constexpr long S1 = 4L * 48 * 24 * 24 * 24;
static constexpr long S2 = 4L * 32 * 12 * 12 * 12;
static constexpr long S3 = 4L * 16 * 6 * 6 * 6;

typedef float f4 __attribute__((ext_vector_type(4)));

__device__ __forceinline__ f4 ntload(const float* p) {
    return __builtin_nontemporal_load((const f4*)p);
}
__device__ __forceinline__ void ntstore(float* p, f4 v) {
    __builtin_nontemporal_store(v, (f4*)p);
}
__device__ __forceinline__ f4 vmax(f4 a, f4 b) {
    f4 r;
    r[0] = fmaxf(a[0], b[0]); r[1] = fmaxf(a[1], b[1]);
    r[2] = fmaxf(a[2], b[2]); r[3] = fmaxf(a[3], b[3]);
    return r;
}

// ---------------------------------------------------------------------------
// K1 body A: pool stage 1 (48->24), register-only, nt input reads.
// pid in [0,6912) = [b(4)][c(48)][zc(12)] x tz(3); block does 2 z-out slices.
// ---------------------------------------------------------------------------
__device__ __forceinline__ void pool1_body(int pid,
                                           const float* __restrict__ q,
                                           const float* __restrict__ k,
                                           const float* __restrict__ v,
                                           float* __restrict__ P1)
{
    const int tz = pid % 3;
    int rest = pid / 3;
    const int zc = rest % 12; rest /= 12;
    const int c = rest % 48;
    const int b = rest / 48;
    const float* in = tz == 0 ? q : (tz == 1 ? k : v);
    float* o = P1 + (long)tz * S1;
    const float* base = in + ((long)b * 64 + 16 + c) * 110592;

    for (int i = threadIdx.x; i < 288; i += 256) {
        const int zl = i / 144;
        const int rem = i % 144;
        const int oy = rem / 6;
        const int qx = rem % 6;
        const int oz = zc * 2 + zl;
        const float* p = base + ((long)(2 * oz) * 48 + 2 * oy) * 48 + qx * 8;
        f4 r0a = ntload(p),        r0b = ntload(p + 4);
        f4 r1a = ntload(p + 48),   r1b = ntload(p + 52);
        f4 r2a = ntload(p + 2304), r2b = ntload(p + 2308);
        f4 r3a = ntload(p + 2352), r3b = ntload(p + 2356);
        f4 ma = vmax(vmax(r0a, r1a), vmax(r2a, r3a));
        f4 mb = vmax(vmax(r0b, r1b), vmax(r2b, r3b));
        f4 res;
        res[0] = fmaxf(ma[0], ma[1]);
        res[1] = fmaxf(ma[2], ma[3]);
        res[2] = fmaxf(mb[0], mb[1]);
        res[3] = fmaxf(mb[2], mb[3]);
        long oaddr = (((long)b * 48 + c) * 24 + oz) * 576 + oy * 24 + qx * 4;
        *(f4*)(o + oaddr) = res;
    }
}

// ---------------------------------------------------------------------------
// K1 body B: fused attn<0> + identity scatter<0>. aid in [0,4096):
// [half(2)][Wy(16)][Wz(16)][head(2)][b(4)]. Tile [wxl][tz][cph][tok pad28]:
// conflict-free LDS. nt in, nt out.
// ---------------------------------------------------------------------------
__device__ __forceinline__ void attn0_body(int aid, float* smem,
                                           const float* __restrict__ qsrc,
                                           const float* __restrict__ ksrc,
                                           const float* __restrict__ vsrc,
                                           const float* __restrict__ rpb,
                                           float* __restrict__ out)
{
    float* tile = smem;           // 8*3*8*28 = 5376
    float* bias = smem + 5376;    // 729
    const int tid = threadIdx.x;
    int rest = aid;
    const int half = rest & 1; rest >>= 1;
    const int Wy = rest % 16; rest /= 16;
    const int Wz = rest % 16; rest /= 16;
    const int head = rest % 2;
    const int b = rest / 2;

    for (int i = tid; i < 729; i += 256) {
        int m = i / 27, n = i % 27;
        int mi = m / 9, mj = (m / 3) % 3, mk = m % 3;
        int ni = n / 9, nj = (n / 3) % 3, nk = n % 3;
        int ridx = (mi - ni + 2) * 25 + (mj - nj + 2) * 5 + (mk - nk + 2);
        bias[i] = rpb[ridx * 2 + head];
    }

    for (int i = tid; i < 1296; i += 256) {
        int seg = i / 6;
        int off = (i % 6) * 4;
        int tz = seg / 72;
        int rem = seg % 72;
        int cph = rem / 9;
        int rem2 = rem % 9;
        int zt = rem2 / 3;
        int r = rem2 % 3;
        const float* src = tz == 0 ? qsrc : (tz == 1 ? ksrc : vsrc);
        long addr = ((((long)b * 64 + head * 8 + cph) * 48 + 3 * Wz + zt) * 48
                     + 3 * Wy + r) * 48 + half * 24 + off;
        f4 f = ntload(src + addr);
#pragma unroll
        for (int j = 0; j < 4; j++) {
            int xl = off + j;
            int wxl = xl / 3, tk = xl - wxl * 3;
            int tok = zt * 9 + r * 3 + tk;
            tile[((wxl * 3 + tz) * 8 + cph) * 28 + tok] = f[j];
        }
    }
    __syncthreads();

    const int wx = tid >> 5;
    const int lane = tid & 31;
    if (lane < 27) {
        const int m = lane;
        float* b0 = tile + wx * 672;
        const float* kb = b0 + 224;
        const float* vb = b0 + 448;
        float qr[8];
#pragma unroll
        for (int c = 0; c < 8; c++) qr[c] = b0[c * 28 + m];

        float s[27];
        float mx = -1e30f;
#pragma unroll
        for (int n = 0; n < 27; n++) {
            float acc = 0.f;
#pragma unroll
            for (int c = 0; c < 8; c++) acc += qr[c] * kb[c * 28 + n];
            acc *= 0.35355339059327373f;  // 1/sqrt(8)
            s[n] = acc;
            mx = fmaxf(mx, acc);
        }
        float sum = 0.f;
#pragma unroll
        for (int n = 0; n < 27; n++) {
            s[n] = __expf(s[n] - mx);
            sum += s[n];
        }
        float rs = 1.0f / sum;
        float o[8] = {0, 0, 0, 0, 0, 0, 0, 0};
#pragma unroll
        for (int n = 0; n < 27; n++) {
            float w = s[n] * rs + bias[m * 27 + n];
#pragma unroll
            for (int c = 0; c < 8; c++) o[c] += w * vb[c * 28 + n];
        }
#pragma unroll
        for (int c = 0; c < 8; c++) b0[c * 28 + m] = o[c];
    }
    __syncthreads();

    for (int i = tid; i < 432; i += 256) {
        int x4i = i % 6;
        int t2 = i / 6;
        int cph = t2 % 8; t2 /= 8;
        int y = t2 % 3;
        int zl = t2 / 3;
        f4 res;
#pragma unroll
        for (int e = 0; e < 4; e++) {
            int xl = x4i * 4 + e;
            int wxl = xl / 3, tk = xl - wxl * 3;
            int tok = zl * 9 + y * 3 + tk;
            res[e] = tile[wxl * 672 + cph * 28 + tok];
        }
        int z = 3 * Wz + zl;
        int Y = 3 * Wy + y;
        long oaddr = (((long)(b * 64 + head * 8 + cph) * 48 + z) * 48 + Y) * 48
                     + half * 24 + x4i * 4;
        ntstore(out + oaddr, res);
    }
}

__global__ void fused_k1(const float* __restrict__ q, const float* __restrict__ k,
                         const float* __restrict__ v, const float* __restrict__ rpb,
                         float* __restrict__ P1, float* __restrict__ out)
{
    __shared__ __align__(16) float smem[6105];
    const int bx = blockIdx.x;
    if (bx < 8192 && (bx & 1) == 0) {
        attn0_body(bx >> 1, smem, q, k, v, rpb, out);   // 4096 attn blocks
    } else {
        int pid = (bx < 8192) ? (bx >> 1) : (bx - 4096); // 6912 pool blocks
        pool1_body(pid, q, k, v, P1);
    }
}

// ---------------------------------------------------------------------------
// Pool stages 2+3 fused: block per (tz,b,c2); stages P1->P2 in LDS, and if
// c2>=16 also P2->P3 from the in-LDS tile.
// ---------------------------------------------------------------------------
__global__ void pool23_kernel(const float* __restrict__ P1,
                              float* __restrict__ P2, float* __restrict__ P3)
{
    __shared__ __align__(16) float vol[13824];
    __shared__ __align__(16) float p2b[1728];
    int bx = blockIdx.x;
    const int c2 = bx % 32; bx /= 32;
    const int b = bx % 4;
    const int tz = bx / 4;
    const float* src = P1 + (long)tz * S1 + ((long)b * 48 + c2 + 16) * 13824;
    for (int i = threadIdx.x; i < 3456; i += 256)
        *(f4*)(vol + 4 * i) = *(const f4*)(src + 4 * i);
    __syncthreads();

    float* o2 = P2 + (long)tz * S2 + ((long)b * 32 + c2) * 1728;
    for (int i = threadIdx.x; i < 432; i += 256) {
        const int x4 = i % 3;
        const int t = i / 3;
        const int y = t % 12;
        const int z = t / 12;
        const float* p0 = vol + (2 * z * 24 + 2 * y) * 24 + x4 * 8;
        f4 res;
#pragma unroll
        for (int e = 0; e < 4; e++) {
            float m0 = fmaxf(p0[2 * e], p0[2 * e + 1]);
            float m1 = fmaxf(p0[24 + 2 * e], p0[24 + 2 * e + 1]);
            float m2 = fmaxf(p0[576 + 2 * e], p0[576 + 2 * e + 1]);
            float m3 = fmaxf(p0[600 + 2 * e], p0[600 + 2 * e + 1]);
            res[e] = fmaxf(fmaxf(m0, m1), fmaxf(m2, m3));
        }
        const int oidx = (z * 12 + y) * 12 + x4 * 4;
        *(f4*)(o2 + oidx) = res;
        *(f4*)(p2b + oidx) = res;
    }
    __syncthreads();

    if (c2 >= 16) {
        float* o3 = P3 + (long)tz * S3 + ((long)b * 16 + (c2 - 16)) * 216;
        for (int i = threadIdx.x; i < 108; i += 256) {
            const int x2 = i % 3;
            const int t = i / 3;
            const int y = t % 6;
            const int z = t / 6;
            const float* p0 = p2b + (2 * z * 12 + 2 * y) * 12 + x2 * 4;
            float r0 = fmaxf(fmaxf(p0[0], p0[1]), fmaxf(p0[12], p0[13]));
            float r1 = fmaxf(fmaxf(p0[144], p0[145]), fmaxf(p0[156], p0[157]));
            float s0 = fmaxf(fmaxf(p0[2], p0[3]), fmaxf(p0[14], p0[15]));
            float s1 = fmaxf(fmaxf(p0[146], p0[147]), fmaxf(p0[158], p0[159]));
            float2 res = make_float2(fmaxf(r0, r1), fmaxf(s0, s1));
            *(float2*)(o3 + (z * 6 + y) * 6 + x2 * 2) = res;
        }
    }
}

// ---------------------------------------------------------------------------
// Fused attention + trilinear scatter for scales 1,2. Block per
// (b,head,Wz,Wy), 256 threads; N1 windows along Wx live in LDS; output
// region written directly (no inter buffer).
// ---------------------------------------------------------------------------
template <int S>
__global__ void attn_sc_kernel(const float* __restrict__ qsrc,
                               const float* __restrict__ ksrc,
                               const float* __restrict__ vsrc,
                               const float* __restrict__ rpb,
                               float* __restrict__ out)
{
    constexpr int N1 = (S == 1 ? 8 : 4);
    constexpr int D = 3 * N1;
    constexpr int bw = 48 / N1;
    constexpr int Cs = (S == 1 ? 48 : 32);
    constexpr int SEGF4 = 3 * D / 4;
    __shared__ float tile[N1 * 672];
    __shared__ float bias[729];
    const int b = blockIdx.z, head = blockIdx.y;
    const int Wz = blockIdx.x / N1, Wy = blockIdx.x % N1;
    const int tid = threadIdx.x;

    for (int i = tid; i < 729; i += 256) {
        int m = i / 27, n = i % 27;
        int mi = m / 9, mj = (m / 3) % 3, mk = m % 3;
        int ni = n / 9, nj = (n / 3) % 3, nk = n % 3;
        int ridx = (mi - ni + 2) * 25 + (mj - nj + 2) * 5 + (mk - nk + 2);
        bias[i] = rpb[ridx * 2 + head];
    }

    for (int i = tid; i < 72 * SEGF4; i += 256) {
        int seg = i / SEGF4;
        int off = (i % SEGF4) * 4;
        int tz = seg / 24;
        int rem = seg % 24;
        int cph = rem / 3;
        int zt = rem % 3;
        const float* src = tz == 0 ? qsrc : (tz == 1 ? ksrc : vsrc);
        long base = ((((long)b * Cs + head * 8 + cph) * D + 3 * Wz + zt) * D + 3 * Wy) * (long)D;
        float4 f = *(const float4*)(src + base + off);
        float vals[4] = {f.x, f.y, f.z, f.w};
#pragma unroll
        for (int j = 0; j < 4; j++) {
            int xl = off + j;
            int r = xl / D;
            int x = xl - r * D;
            int wxl = x / 3, tk = x - wxl * 3;
            tile[((wxl * 3 + tz) * 8 + cph) * 28 + zt * 9 + r * 3 + tk] = vals[j];
        }
    }
    __syncthreads();

    const int wx = tid >> 5;
    const int lane = tid & 31;
    if (wx < N1 && lane < 27) {
        const int m = lane;
        float* b0 = tile + wx * 672;
        const float* kb = b0 + 224;
        const float* vb = b0 + 448;
        float qr[8];
#pragma unroll
        for (int c = 0; c < 8; c++) qr[c] = b0[c * 28 + m];
        float s[27];
        float mx = -1e30f;
#pragma unroll
        for (int n = 0; n < 27; n++) {
            float acc = 0.f;
#pragma unroll
            for (int c = 0; c < 8; c++) acc += qr[c] * kb[c * 28 + n];
            acc *= 0.35355339059327373f;
            s[n] = acc;
            mx = fmaxf(mx, acc);
        }
        float sum = 0.f;
#pragma unroll
        for (int n = 0; n < 27; n++) {
            s[n] = __expf(s[n] - mx);
            sum += s[n];
        }
        float rs = 1.0f / sum;
        float o[8] = {0, 0, 0, 0, 0, 0, 0, 0};
#pragma unroll
        for (int n = 0; n < 27; n++) {
            float w = s[n] * rs + bias[m * 27 + n];
#pragma unroll
            for (int c = 0; c < 8; c++) o[c] += w * vb[c * 28 + n];
        }
#pragma unroll
        for (int c = 0; c < 8; c++) b0[c * 28 + m] = o[c];
    }
    __syncthreads();

    constexpr int NF4 = bw * bw * 96;
    const float inv = 2.0f / (float)(bw - 1);
    for (int i = tid; i < NF4; i += 256) {
        int x4 = i % 12;
        int t2 = i / 12;
        int cph = t2 % 8; t2 /= 8;
        int wq = t2 % bw;
        int wp = t2 / bw;
        float posp = wp * inv; int i0p = min((int)posp, 1); float fp = posp - (float)i0p;
        float posq = wq * inv; int i0q = min((int)posq, 1); float fq = posq - (float)i0q;
        float wpv[2] = {1.f - fp, fp};
        float wqv[2] = {1.f - fq, fq};
        f4 res;
#pragma unroll
        for (int e = 0; e < 4; e++) {
            int xg = x4 * 4 + e;
            int Wx = xg / bw, wr = xg - Wx * bw;
            float posr = wr * inv; int i0r = min((int)posr, 1); float fr = posr - (float)i0r;
            float wrv[2] = {1.f - fr, fr};
            const float* bp = tile + Wx * 672 + cph * 28;
            float acc = 0.f;
#pragma unroll
            for (int di = 0; di < 2; di++) {
#pragma unroll
                for (int dj = 0; dj < 2; dj++) {
#pragma unroll
                    for (int dk = 0; dk < 2; dk++) {
                        int tok = ((i0p + di) * 3 + (i0q + dj)) * 3 + (i0r + dk);
                        acc += wpv[di] * wqv[dj] * wrv[dk] * bp[tok];
                    }
                }
            }
            res[e] = acc;
        }
        long oaddr = (((long)(b * 64 + S * 16 + head * 8 + cph) * 48 + Wz * bw + wp) * 48
                      + Wy * bw + wq) * 48 + x4 * 4;
        ntstore(out + oaddr, res);
    }
}

// ---------------------------------------------------------------------------
// Scale 3 attention (writes inter buffer) + standalone scatter.
// ---------------------------------------------------------------------------
__global__ void attn3_kernel(const float* __restrict__ qsrc,
                             const float* __restrict__ ksrc,
                             const float* __restrict__ vsrc,
                             const float* __restrict__ rpb,
                             float* __restrict__ attnOut)
{
    __shared__ float tile[2][3][27][8];
    __shared__ float bias[729];
    const int b = blockIdx.z, head = blockIdx.y;
    const int Wz = blockIdx.x / 2, Wy = blockIdx.x % 2;
    const int tid = threadIdx.x;

    for (int i = tid; i < 729; i += 64) {
        int m = i / 27, n = i % 27;
        int mi = m / 9, mj = (m / 3) % 3, mk = m % 3;
        int ni = n / 9, nj = (n / 3) % 3, nk = n % 3;
        int ridx = (mi - ni + 2) * 25 + (mj - nj + 2) * 5 + (mk - nk + 2);
        bias[i] = rpb[ridx * 2 + head];
    }
    for (int i = tid; i < 648; i += 64) {
        int seg = i / 9;
        int off = (i % 9) * 2;
        int tz = seg / 24;
        int rem = seg % 24;
        int cph = rem / 3;
        int zt = rem % 3;
        const float* src = tz == 0 ? qsrc : (tz == 1 ? ksrc : vsrc);
        long base = ((((long)b * 16 + head * 8 + cph) * 6 + 3 * Wz + zt) * 6 + 3 * Wy) * 6L;
        float2 f = *(const float2*)(src + base + off);
        float vals[2] = {f.x, f.y};
#pragma unroll
        for (int j = 0; j < 2; j++) {
            int xl = off + j;
            int r = xl / 6;
            int x = xl - r * 6;
            tile[x / 3][tz][zt * 9 + r * 3 + (x % 3)][cph] = vals[j];
        }
    }
    __syncthreads();

    const int wx = tid >> 5;
    const int lane = tid & 31;
    if (lane >= 27) return;
    const int m = lane;
    float qr[8];
#pragma unroll
    for (int c = 0; c < 8; c++) qr[c] = tile[wx][0][m][c];
    float s[27];
    float mx = -1e30f;
#pragma unroll
    for (int n = 0; n < 27; n++) {
        float acc = 0.f;
#pragma unroll
        for (int c = 0; c < 8; c++) acc += qr[c] * tile[wx][1][n][c];
        acc *= 0.35355339059327373f;
        s[n] = acc;
        mx = fmaxf(mx, acc);
    }
    float sum = 0.f;
#pragma unroll
    for (int n = 0; n < 27; n++) {
        s[n] = __expf(s[n] - mx);
        sum += s[n];
    }
    float rs = 1.0f / sum;
    float o[8] = {0, 0, 0, 0, 0, 0, 0, 0};
#pragma unroll
    for (int n = 0; n < 27; n++) {
        float w = s[n] * rs + bias[m * 27 + n];
#pragma unroll
        for (int c = 0; c < 8; c++) o[c] += w * tile[wx][2][n][c];
    }
    const int win = (Wz * 2 + Wy) * 2 + wx;
    float* dst = attnOut + (((long)(b * 2 + head) * 4680 + 4672 + win) * 27 + m) * 8;
    *(float4*)(dst) = make_float4(o[0], o[1], o[2], o[3]);
    *(float4*)(dst + 4) = make_float4(o[4], o[5], o[6], o[7]);
}

__global__ void scatter3_kernel(const float* __restrict__ attn, float* __restrict__ out)
{
    __shared__ __align__(16) float lds[432];
    const int b = blockIdx.z, head = blockIdx.y;
    int t = blockIdx.x;
    const int zc = t % 24; t /= 24;
    const int Wy = t % 2;
    const int Wz = t / 2;
    const float* src = attn + ((long)(b * 2 + head) * 4680 + 4672 + (Wz * 2 + Wy) * 2) * 216;
    for (int i = threadIdx.x; i < 108; i += 256)
        *(f4*)(lds + 4 * i) = *(const f4*)(src + 4 * i);
    __syncthreads();

    const float inv = 2.0f / 23.0f;
    for (int i = threadIdx.x; i < 2304; i += 256) {
        int x4 = i % 12;
        int t2 = i / 12;
        int cph = t2 % 8;
        int y = t2 / 8;          // 0..23
        int wp = zc;
        float posp = wp * inv; int i0p = min((int)posp, 1); float fp = posp - (float)i0p;
        float posq = y * inv;  int i0q = min((int)posq, 1); float fq = posq - (float)i0q;
        float wpv[2] = {1.f - fp, fp};
        float wqv[2] = {1.f - fq, fq};
        f4 res;
#pragma unroll
        for (int e = 0; e < 4; e++) {
            int r = x4 * 4 + e;
            int Wx = r / 24, wr = r % 24;
            float posr = wr * inv; int i0r = min((int)posr, 1); float fr = posr - (float)i0r;
            float wrv[2] = {1.f - fr, fr};
            const float* basep = lds + Wx * 216 + cph;
            float acc = 0.f;
#pragma unroll
            for (int di = 0; di < 2; di++) {
#pragma unroll
                for (int dj = 0; dj < 2; dj++) {
#pragma unroll
                    for (int dk = 0; dk < 2; dk++) {
                        int tok = ((i0p + di) * 3 + (i0q + dj)) * 3 + (i0r + dk);
                        acc += wpv[di] * wqv[dj] * wrv[dk] * basep[tok * 8];
                    }
                }
            }
            res[e] = acc;
        }
        int z = Wz * 24 + wp;
        int Y = Wy * 24 + y;
        long oaddr = (((long)(b * 64 + 48 + head * 8 + cph) * 48 + z) * 48 + Y) * 48 + x4 * 4;
        ntstore(out + oaddr, res);
    }
}

extern "C" void kernel_launch(void* const* d_in, const int* in_sizes, int n_in,
                              void* d_out, int out_size, void* d_ws, size_t ws_size,
                              hipStream_t stream)
{
    const float* q   = (const float*)d_in[0];
    const float* k   = (const float*)d_in[1];
    const float* v   = (const float*)d_in[2];
    const float* rpb = (const float*)d_in[3];
    float* out = (float*)d_out;

    float* ws = (float*)d_ws;
    float* P1 = ws;
    float* P2 = ws + 3 * S1;
    float* P3 = ws + 3 * S1 + 3 * S2;
    float* attn = ws + 3 * S1 + 3 * S2 + 3 * S3;

    // K1: pool stage 1 (6912 blocks) co-launched with fused attn0+scatter0 (4096)
    fused_k1<<<11008, 256, 0, stream>>>(q, k, v, rpb, P1, out);

    // Pool stages 2+3 fused
    pool23_kernel<<<384, 256, 0, stream>>>(P1, P2, P3);

    // Attention + fused trilinear scatter, scales 1,2
    attn_sc_kernel<1><<<dim3(64, 2, 4), 256, 0, stream>>>(P1, P1 + S1, P1 + 2 * S1, rpb, out);
    attn_sc_kernel<2><<<dim3(16, 2, 4), 256, 0, stream>>>(P2, P2 + S2, P2 + 2 * S2, rpb, out);

    // Scale 3: attention -> inter, then scatter
    attn3_kernel<<<dim3(4, 2, 4), 64, 0, stream>>>(P3, P3 + S3, P3 + 2 * S3, rpb, attn);
    scatter3_kernel<<<dim3(96, 2, 4), 256, 0, stream>>>(attn, out);
}

// Round 8
// 174.339 us; speedup vs baseline: 1.2432x; 1.2432x over previous
//
#include <hip/hip_runtime.h>

// B=4, C=64, H=48, HEADS=2, BSWIN=4, BIG={3,6,12,24}, SMALL={1,2,4,8}, NH=3, L=27, CPH=8
// channel c = scale*16 + head*8 + cph
// P1 = 2x-pooled raw channels 16..63 (48 ch), stored bf16: [tz][b][ch][24][24][24]

typedef unsigned short u16;
static constexpr long S1 = 4L * 48 * 24 * 24 * 24;   // elements per tensor in P1

typedef float f4 __attribute__((ext_vector_type(4)));
typedef u16 us8 __attribute__((ext_vector_type(8)));
typedef u16 us4 __attribute__((ext_vector_type(4)));

__device__ __forceinline__ f4 ntload(const float* p) {
    return __builtin_nontemporal_load((const f4*)p);
}
__device__ __forceinline__ void ntstore(float* p, f4 v) {
    __builtin_nontemporal_store(v, (f4*)p);
}
__device__ __forceinline__ f4 vmax4(f4 a, f4 b) {
    f4 r;
    r[0] = fmaxf(a[0], b[0]); r[1] = fmaxf(a[1], b[1]);
    r[2] = fmaxf(a[2], b[2]); r[3] = fmaxf(a[3], b[3]);
    return r;
}
__device__ __forceinline__ float b2f(u16 u) {
    union { unsigned int i; float f; } c; c.i = ((unsigned int)u) << 16; return c.f;
}
__device__ __forceinline__ u16 f2b(float x) {
    union { float f; unsigned int i; } c; c.f = x;
    unsigned int b = c.i;
    return (u16)((b + 0x7FFFu + ((b >> 16) & 1u)) >> 16);
}

// ---------------------------------------------------------------------------
// K1 body A: pool stage 1 (48->24), nt input reads, bf16 output.
// pid in [0,6912) = [b(4)][c(48)][zc(12)] x tz(3)
// ---------------------------------------------------------------------------
__device__ __forceinline__ void pool1_body(int pid,
                                           const float* __restrict__ q,
                                           const float* __restrict__ k,
                                           const float* __restrict__ v,
                                           u16* __restrict__ P1)
{
    const int tz = pid % 3;
    int rest = pid / 3;
    const int zc = rest % 12; rest /= 12;
    const int c = rest % 48;
    const int b = rest / 48;
    const float* in = tz == 0 ? q : (tz == 1 ? k : v);
    u16* o = P1 + (long)tz * S1;
    const float* base = in + ((long)b * 64 + 16 + c) * 110592;

    for (int i = threadIdx.x; i < 288; i += 256) {
        const int zl = i / 144;
        const int rem = i % 144;
        const int oy = rem / 6;
        const int qx = rem % 6;
        const int oz = zc * 2 + zl;
        const float* p = base + ((long)(2 * oz) * 48 + 2 * oy) * 48 + qx * 8;
        f4 r0a = ntload(p),        r0b = ntload(p + 4);
        f4 r1a = ntload(p + 48),   r1b = ntload(p + 52);
        f4 r2a = ntload(p + 2304), r2b = ntload(p + 2308);
        f4 r3a = ntload(p + 2352), r3b = ntload(p + 2356);
        f4 ma = vmax4(vmax4(r0a, r1a), vmax4(r2a, r3a));
        f4 mb = vmax4(vmax4(r0b, r1b), vmax4(r2b, r3b));
        us4 res;
        res[0] = f2b(fmaxf(ma[0], ma[1]));
        res[1] = f2b(fmaxf(ma[2], ma[3]));
        res[2] = f2b(fmaxf(mb[0], mb[1]));
        res[3] = f2b(fmaxf(mb[2], mb[3]));
        long oaddr = (((long)b * 48 + c) * 24 + oz) * 576 + oy * 24 + qx * 4;
        *(us4*)(o + oaddr) = res;
    }
}

// ---------------------------------------------------------------------------
// K1 body B: fused attn<0> + identity scatter<0> (proven in round 7).
// aid in [0,4096): [half(2)][Wy(16)][Wz(16)][head(2)][b(4)]
// ---------------------------------------------------------------------------
__device__ __forceinline__ void attn0_body(int aid, float* smem,
                                           const float* __restrict__ qsrc,
                                           const float* __restrict__ ksrc,
                                           const float* __restrict__ vsrc,
                                           const float* __restrict__ rpb,
                                           float* __restrict__ out)
{
    float* tile = smem;           // 8*3*8*28 = 5376
    float* bias = smem + 5376;    // 729
    const int tid = threadIdx.x;
    int rest = aid;
    const int half = rest & 1; rest >>= 1;
    const int Wy = rest % 16; rest /= 16;
    const int Wz = rest % 16; rest /= 16;
    const int head = rest % 2;
    const int b = rest / 2;

    for (int i = tid; i < 729; i += 256) {
        int m = i / 27, n = i % 27;
        int mi = m / 9, mj = (m / 3) % 3, mk = m % 3;
        int ni = n / 9, nj = (n / 3) % 3, nk = n % 3;
        int ridx = (mi - ni + 2) * 25 + (mj - nj + 2) * 5 + (mk - nk + 2);
        bias[i] = rpb[ridx * 2 + head];
    }

    for (int i = tid; i < 1296; i += 256) {
        int seg = i / 6;
        int off = (i % 6) * 4;
        int tz = seg / 72;
        int rem = seg % 72;
        int cph = rem / 9;
        int rem2 = rem % 9;
        int zt = rem2 / 3;
        int r = rem2 % 3;
        const float* src = tz == 0 ? qsrc : (tz == 1 ? ksrc : vsrc);
        long addr = ((((long)b * 64 + head * 8 + cph) * 48 + 3 * Wz + zt) * 48
                     + 3 * Wy + r) * 48 + half * 24 + off;
        f4 f = ntload(src + addr);
#pragma unroll
        for (int j = 0; j < 4; j++) {
            int xl = off + j;
            int wxl = xl / 3, tk = xl - wxl * 3;
            int tok = zt * 9 + r * 3 + tk;
            tile[((wxl * 3 + tz) * 8 + cph) * 28 + tok] = f[j];
        }
    }
    __syncthreads();

    const int wx = tid >> 5;
    const int lane = tid & 31;
    if (lane < 27) {
        const int m = lane;
        float* b0 = tile + wx * 672;
        const float* kb = b0 + 224;
        const float* vb = b0 + 448;
        float qr[8];
#pragma unroll
        for (int c = 0; c < 8; c++) qr[c] = b0[c * 28 + m];
        float s[27];
        float mx = -1e30f;
#pragma unroll
        for (int n = 0; n < 27; n++) {
            float acc = 0.f;
#pragma unroll
            for (int c = 0; c < 8; c++) acc += qr[c] * kb[c * 28 + n];
            acc *= 0.35355339059327373f;  // 1/sqrt(8)
            s[n] = acc;
            mx = fmaxf(mx, acc);
        }
        float sum = 0.f;
#pragma unroll
        for (int n = 0; n < 27; n++) {
            s[n] = __expf(s[n] - mx);
            sum += s[n];
        }
        float rs = 1.0f / sum;
        float o[8] = {0, 0, 0, 0, 0, 0, 0, 0};
#pragma unroll
        for (int n = 0; n < 27; n++) {
            float w = s[n] * rs + bias[m * 27 + n];
#pragma unroll
            for (int c = 0; c < 8; c++) o[c] += w * vb[c * 28 + n];
        }
#pragma unroll
        for (int c = 0; c < 8; c++) b0[c * 28 + m] = o[c];
    }
    __syncthreads();

    for (int i = tid; i < 432; i += 256) {
        int x4i = i % 6;
        int t2 = i / 6;
        int cph = t2 % 8; t2 /= 8;
        int y = t2 % 3;
        int zl = t2 / 3;
        f4 res;
#pragma unroll
        for (int e = 0; e < 4; e++) {
            int xl = x4i * 4 + e;
            int wxl = xl / 3, tk = xl - wxl * 3;
            int tok = zl * 9 + y * 3 + tk;
            res[e] = tile[wxl * 672 + cph * 28 + tok];
        }
        int z = 3 * Wz + zl;
        int Y = 3 * Wy + y;
        long oaddr = (((long)(b * 64 + head * 8 + cph) * 48 + z) * 48 + Y) * 48
                     + half * 24 + x4i * 4;
        ntstore(out + oaddr, res);
    }
}

__global__ void fused_k1(const float* __restrict__ q, const float* __restrict__ k,
                         const float* __restrict__ v, const float* __restrict__ rpb,
                         u16* __restrict__ P1, float* __restrict__ out)
{
    __shared__ __align__(16) float smem[6105];
    const int bx = blockIdx.x;
    if (bx < 8192 && (bx & 1) == 0) {
        attn0_body(bx >> 1, smem, q, k, v, rpb, out);
    } else {
        int pid = (bx < 8192) ? (bx >> 1) : (bx - 4096);
        pool1_body(pid, q, k, v, P1);
    }
}

// ---------------------------------------------------------------------------
// K2: attention + trilinear scatter for scales 1..3, all from bf16 P1.
//   bx <  64 : class C (scale 3) — block per (b,head,win), self-pools 4x
//   bx < 192 : class B (scale 2) — block per (b,head,Wz,Wy), self-pools 2x
//   else     : class A (scale 1) — block per (b,head,Wz,Wy), tokens = P1 cells
// Tile layout [wxl][tz][cph][tok pad28]; bias at smem+5376.
// ---------------------------------------------------------------------------
__device__ __forceinline__ void load_bias(float* bias, const float* __restrict__ rpb,
                                          int head, int tid)
{
    for (int i = tid; i < 729; i += 256) {
        int m = i / 27, n = i % 27;
        int mi = m / 9, mj = (m / 3) % 3, mk = m % 3;
        int ni = n / 9, nj = (n / 3) % 3, nk = n % 3;
        int ridx = (mi - ni + 2) * 25 + (mj - nj + 2) * 5 + (mk - nk + 2);
        bias[i] = rpb[ridx * 2 + head];
    }
}

__device__ __forceinline__ void attn_tile(float* tile, const float* bias, int tid, int NW)
{
    const int wx = tid >> 5;
    const int lane = tid & 31;
    if (wx < NW && lane < 27) {
        const int m = lane;
        float* b0 = tile + wx * 672;
        const float* kb = b0 + 224;
        const float* vb = b0 + 448;
        float qr[8];
#pragma unroll
        for (int c = 0; c < 8; c++) qr[c] = b0[c * 28 + m];
        float s[27];
        float mx = -1e30f;
#pragma unroll
        for (int n = 0; n < 27; n++) {
            float acc = 0.f;
#pragma unroll
            for (int c = 0; c < 8; c++) acc += qr[c] * kb[c * 28 + n];
            acc *= 0.35355339059327373f;
            s[n] = acc;
            mx = fmaxf(mx, acc);
        }
        float sum = 0.f;
#pragma unroll
        for (int n = 0; n < 27; n++) {
            s[n] = __expf(s[n] - mx);
            sum += s[n];
        }
        float rs = 1.0f / sum;
        float o[8] = {0, 0, 0, 0, 0, 0, 0, 0};
#pragma unroll
        for (int n = 0; n < 27; n++) {
            float w = s[n] * rs + bias[m * 27 + n];
#pragma unroll
            for (int c = 0; c < 8; c++) o[c] += w * vb[c * 28 + n];
        }
#pragma unroll
        for (int c = 0; c < 8; c++) b0[c * 28 + m] = o[c];
    }
}

__global__ void fused_k2(const u16* __restrict__ P1, const float* __restrict__ rpb,
                         float* __restrict__ out)
{
    __shared__ __align__(16) float smem[6105];
    float* tile = smem;
    float* bias = smem + 5376;
    const int tid = threadIdx.x;
    const int bx = blockIdx.x;

    if (bx >= 192) {
        // ------------------ class A: scale 1 (bw=6, N1=8) ------------------
        int aid = bx - 192;
        const int Wy = aid % 8; aid /= 8;
        const int Wz = aid % 8; aid /= 8;
        const int head = aid % 2;
        const int b = aid / 2;
        load_bias(bias, rpb, head, tid);
        for (int i = tid; i < 648; i += 256) {
            int xq = i % 3;
            int row = i / 3;
            int tz = row / 72;
            int rem = row % 72;
            int cph = rem / 9;
            int rem2 = rem % 9;
            int zt = rem2 / 3, r = rem2 % 3;
            const u16* p = P1 + (long)tz * S1 + ((long)b * 48 + head * 8 + cph) * 13824
                           + (3 * Wz + zt) * 576 + (3 * Wy + r) * 24 + xq * 8;
            us8 u = *(const us8*)p;
#pragma unroll
            for (int j = 0; j < 8; j++) {
                int xl = xq * 8 + j;
                int wxl = xl / 3, tk = xl - wxl * 3;
                tile[((wxl * 3 + tz) * 8 + cph) * 28 + zt * 9 + r * 3 + tk] = b2f(u[j]);
            }
        }
        __syncthreads();
        attn_tile(tile, bias, tid, 8);
        __syncthreads();

        const float inv = 2.0f / 5.0f;
        for (int i = tid; i < 3456; i += 256) {
            int x4 = i % 12;
            int t2 = i / 12;
            int cph = t2 % 8; t2 /= 8;
            int wq = t2 % 6;
            int wp = t2 / 6;
            float posp = wp * inv; int i0p = min((int)posp, 1); float fp = posp - (float)i0p;
            float posq = wq * inv; int i0q = min((int)posq, 1); float fq = posq - (float)i0q;
            float wpv[2] = {1.f - fp, fp};
            float wqv[2] = {1.f - fq, fq};
            f4 res;
#pragma unroll
            for (int e = 0; e < 4; e++) {
                int xg = x4 * 4 + e;
                int Wx = xg / 6, wr = xg - Wx * 6;
                float posr = wr * inv; int i0r = min((int)posr, 1); float fr = posr - (float)i0r;
                float wrv[2] = {1.f - fr, fr};
                const float* bp = tile + Wx * 672 + cph * 28;
                float acc = 0.f;
#pragma unroll
                for (int di = 0; di < 2; di++)
#pragma unroll
                    for (int dj = 0; dj < 2; dj++)
#pragma unroll
                        for (int dk = 0; dk < 2; dk++) {
                            int tok = ((i0p + di) * 3 + (i0q + dj)) * 3 + (i0r + dk);
                            acc += wpv[di] * wqv[dj] * wrv[dk] * bp[tok];
                        }
                res[e] = acc;
            }
            long oaddr = (((long)(b * 64 + 16 + head * 8 + cph) * 48 + 6 * Wz + wp) * 48
                          + 6 * Wy + wq) * 48 + x4 * 4;
            ntstore(out + oaddr, res);
        }
    } else if (bx >= 64) {
        // ------------------ class B: scale 2 (bw=12, N1=4), self-pool 2x ---
        int bid = bx - 64;
        const int Wy = bid % 4; bid /= 4;
        const int Wz = bid % 4; bid /= 4;
        const int head = bid % 2;
        const int b = bid / 2;
        load_bias(bias, rpb, head, tid);
        for (int i = tid; i < 648; i += 256) {
            int xq = i % 3;
            int t = i / 3;
            int yt = t % 3; t /= 3;
            int zt = t % 3; t /= 3;
            int cph = t % 8;
            int tz = t / 8;
            const u16* base = P1 + (long)tz * S1 + ((long)b * 48 + 16 + head * 8 + cph) * 13824;
            float tv[4] = {-1e30f, -1e30f, -1e30f, -1e30f};
#pragma unroll
            for (int dz = 0; dz < 2; dz++)
#pragma unroll
                for (int dy = 0; dy < 2; dy++) {
                    const u16* p = base + (6 * Wz + 2 * zt + dz) * 576
                                   + (6 * Wy + 2 * yt + dy) * 24 + xq * 8;
                    us8 u = *(const us8*)p;
#pragma unroll
                    for (int j = 0; j < 4; j++)
                        tv[j] = fmaxf(tv[j], fmaxf(b2f(u[2 * j]), b2f(u[2 * j + 1])));
                }
#pragma unroll
            for (int j = 0; j < 4; j++) {
                int xt = xq * 4 + j;
                int wxl = xt / 3, tk = xt - wxl * 3;
                tile[((wxl * 3 + tz) * 8 + cph) * 28 + zt * 9 + yt * 3 + tk] = tv[j];
            }
        }
        __syncthreads();
        attn_tile(tile, bias, tid, 4);
        __syncthreads();

        const float inv = 2.0f / 11.0f;
        for (int i = tid; i < 13824; i += 256) {
            int x4 = i % 12;
            int t2 = i / 12;
            int cph = t2 % 8; t2 /= 8;
            int wq = t2 % 12;
            int wp = t2 / 12;
            float posp = wp * inv; int i0p = min((int)posp, 1); float fp = posp - (float)i0p;
            float posq = wq * inv; int i0q = min((int)posq, 1); float fq = posq - (float)i0q;
            float wpv[2] = {1.f - fp, fp};
            float wqv[2] = {1.f - fq, fq};
            f4 res;
#pragma unroll
            for (int e = 0; e < 4; e++) {
                int xg = x4 * 4 + e;
                int Wx = xg / 12, wr = xg - Wx * 12;
                float posr = wr * inv; int i0r = min((int)posr, 1); float fr = posr - (float)i0r;
                float wrv[2] = {1.f - fr, fr};
                const float* bp = tile + Wx * 672 + cph * 28;
                float acc = 0.f;
#pragma unroll
                for (int di = 0; di < 2; di++)
#pragma unroll
                    for (int dj = 0; dj < 2; dj++)
#pragma unroll
                        for (int dk = 0; dk < 2; dk++) {
                            int tok = ((i0p + di) * 3 + (i0q + dj)) * 3 + (i0r + dk);
                            acc += wpv[di] * wqv[dj] * wrv[dk] * bp[tok];
                        }
                res[e] = acc;
            }
            long oaddr = (((long)(b * 64 + 32 + head * 8 + cph) * 48 + 12 * Wz + wp) * 48
                          + 12 * Wy + wq) * 48 + x4 * 4;
            ntstore(out + oaddr, res);
        }
    } else {
        // ------------------ class C: scale 3 (bw=24, N1=2), self-pool 4x ---
        int cid = bx;
        const int Wx = cid % 2; cid /= 2;
        const int Wy = cid % 2; cid /= 2;
        const int Wz = cid % 2; cid /= 2;
        const int head = cid % 2;
        const int b = cid / 2;
        load_bias(bias, rpb, head, tid);
        for (int i = tid; i < 216; i += 256) {
            int yt = i % 3;
            int t = i / 3;
            int zt = t % 3; t /= 3;
            int cph = t % 8;
            int tz = t / 8;
            const u16* base = P1 + (long)tz * S1 + ((long)b * 48 + 32 + head * 8 + cph) * 13824;
            float tv[3] = {-1e30f, -1e30f, -1e30f};
#pragma unroll
            for (int dz = 0; dz < 4; dz++)
#pragma unroll
                for (int dy = 0; dy < 4; dy++) {
                    const u16* p = base + (12 * Wz + 4 * zt + dz) * 576
                                   + (12 * Wy + 4 * yt + dy) * 24 + 12 * Wx;
#pragma unroll
                    for (int s3 = 0; s3 < 3; s3++) {
                        us4 u = *(const us4*)(p + 4 * s3);
                        tv[s3] = fmaxf(tv[s3],
                                       fmaxf(fmaxf(b2f(u[0]), b2f(u[1])),
                                             fmaxf(b2f(u[2]), b2f(u[3]))));
                    }
                }
#pragma unroll
            for (int s3 = 0; s3 < 3; s3++)
                tile[(tz * 8 + cph) * 28 + zt * 9 + yt * 3 + s3] = tv[s3];
        }
        __syncthreads();
        attn_tile(tile, bias, tid, 1);
        __syncthreads();

        const float inv = 2.0f / 23.0f;
        for (int i = tid; i < 27648; i += 256) {
            int x4 = i % 6;
            int t2 = i / 6;
            int cph = t2 % 8; t2 /= 8;
            int wq = t2 % 24;
            int wp = t2 / 24;
            float posp = wp * inv; int i0p = min((int)posp, 1); float fp = posp - (float)i0p;
            float posq = wq * inv; int i0q = min((int)posq, 1); float fq = posq - (float)i0q;
            float wpv[2] = {1.f - fp, fp};
            float wqv[2] = {1.f - fq, fq};
            f4 res;
#pragma unroll
            for (int e = 0; e < 4; e++) {
                int wr = x4 * 4 + e;   // window-local x (window covers 24)
                float posr = wr * inv; int i0r = min((int)posr, 1); float fr = posr - (float)i0r;
                float wrv[2] = {1.f - fr, fr};
                const float* bp = tile + cph * 28;
                float acc = 0.f;
#pragma unroll
                for (int di = 0; di < 2; di++)
#pragma unroll
                    for (int dj = 0; dj < 2; dj++)
#pragma unroll
                        for (int dk = 0; dk < 2; dk++) {
                            int tok = ((i0p + di) * 3 + (i0q + dj)) * 3 + (i0r + dk);
                            acc += wpv[di] * wqv[dj] * wrv[dk] * bp[tok];
                        }
                res[e] = acc;
            }
            long oaddr = (((long)(b * 64 + 48 + head * 8 + cph) * 48 + 24 * Wz + wp) * 48
                          + 24 * Wy + wq) * 48 + 24 * Wx + x4 * 4;
            ntstore(out + oaddr, res);
        }
    }
}

extern "C" void kernel_launch(void* const* d_in, const int* in_sizes, int n_in,
                              void* d_out, int out_size, void* d_ws, size_t ws_size,
                              hipStream_t stream)
{
    const float* q   = (const float*)d_in[0];
    const float* k   = (const float*)d_in[1];
    const float* v   = (const float*)d_in[2];
    const float* rpb = (const float*)d_in[3];
    float* out = (float*)d_out;
    u16* P1 = (u16*)d_ws;   // 3 * S1 bf16 = 31.9 MB

    // K1: pool stage 1 (bf16 out) co-launched with fused attn0+scatter0
    fused_k1<<<11008, 256, 0, stream>>>(q, k, v, rpb, P1, out);

    // K2: attention + trilinear scatter for scales 1..3 (one launch)
    fused_k2<<<704, 256, 0, stream>>>(P1, rpb, out);
}